// Round 3
// baseline (889.767 us; speedup 1.0000x reference)
//
#include <hip/hip_runtime.h>
#include <hip/hip_bf16.h>
#include <math.h>

#define NNODES 100000
#define NEDGES 3200000
#define FIN 512
#define HID 8
#define NC 64

// ---- workspace layout (bytes). total ~59.2 MB ----
#define OFF_DEG      0u          // N int
#define OFF_CNT      524288u     // N int
#define OFF_FILL     1048576u    // N int
#define OFF_DINV     1572864u    // N float
#define OFF_COLPTR   2097152u    // N+1 int
#define OFF_BSUM     2621440u    // <=128 int
#define OFF_BOFF     2625536u    // <=128 int
#define OFF_A1       2629632u    // 8 float
#define OFF_A2       2629888u    // 64 float
#define OFF_CSR      3145728u    // E int2 = 25.6 MB
#define OFF_H1       29360128u   // N*8 float = 3.2 MB
#define OFF_H2       33554432u   // N*64 float = 25.6 MB

__global__ __launch_bounds__(256) void k_count(const int* __restrict__ ei,
                                               int* __restrict__ deg, int* __restrict__ cnt) {
    int t = blockIdx.x * blockDim.x + threadIdx.x;
    if (t < NEDGES) {
        atomicAdd(&deg[ei[t]], 1);          // source-degree (row)
        atomicAdd(&cnt[ei[NEDGES + t]], 1); // in-degree (col) for CSR
    }
}

__global__ __launch_bounds__(256) void k_dinv(const int* __restrict__ deg, float* __restrict__ dinv) {
    int t = blockIdx.x * blockDim.x + threadIdx.x;
    if (t < NNODES) {
        int d = deg[t];
        dinv[t] = (d > 0) ? 1.0f / sqrtf((float)d) : 0.0f;
    }
}

__global__ __launch_bounds__(1024) void k_scan1(const int* __restrict__ cnt,
                                                int* __restrict__ colptr, int* __restrict__ bsum) {
    __shared__ int s[1024];
    int t = threadIdx.x, b = blockIdx.x;
    int i = b * 1024 + t;
    int v = (i < NNODES) ? cnt[i] : 0;
    s[t] = v; __syncthreads();
    for (int off = 1; off < 1024; off <<= 1) {
        int add = (t >= off) ? s[t - off] : 0;
        __syncthreads();
        s[t] += add;
        __syncthreads();
    }
    if (i < NNODES) colptr[i + 1] = s[t];
    if (t == 1023) bsum[b] = s[1023];
}

__global__ __launch_bounds__(128) void k_scan2(const int* __restrict__ bsum,
                                               int* __restrict__ boff, int nb) {
    __shared__ int s[128];
    int t = threadIdx.x;
    int v = (t < nb) ? bsum[t] : 0;
    s[t] = v; __syncthreads();
    for (int off = 1; off < 128; off <<= 1) {
        int add = (t >= off) ? s[t - off] : 0;
        __syncthreads();
        s[t] += add;
        __syncthreads();
    }
    if (t < nb) boff[t] = s[t] - v; // exclusive
}

__global__ __launch_bounds__(1024) void k_scan3(int* __restrict__ colptr, const int* __restrict__ boff) {
    int i = blockIdx.x * blockDim.x + threadIdx.x;
    if (i < NNODES) colptr[i + 1] += boff[i >> 10];
    if (i == 0) colptr[0] = 0;
}

// Collapse edge-MLP (exact for norm>=0): A_k = sum_j leaky(mWa_j) * mWb[j][k]
__global__ __launch_bounds__(64) void k_precomp(const float* __restrict__ mW1a, const float* __restrict__ mW1b,
                                                const float* __restrict__ mW2a, const float* __restrict__ mW2b,
                                                float* __restrict__ A1, float* __restrict__ A2) {
    int t = threadIdx.x;
    if (t < 8) {
        float s = 0.f;
        for (int j = 0; j < 8; j++) {
            float a = mW1a[j]; a = a > 0.f ? a : 0.2f * a;
            s += a * mW1b[j * 8 + t];
        }
        A1[t] = s;
    }
    if (t < 64) {
        float s = 0.f;
        for (int j = 0; j < 64; j++) {
            float a = mW2a[j]; a = a > 0.f ? a : 0.2f * a;
            s += a * mW2b[j * 64 + t];
        }
        A2[t] = s;
    }
}

__global__ __launch_bounds__(256) void k_fill(const int* __restrict__ ei, const float* __restrict__ dinv,
                                              const int* __restrict__ colptr, int* __restrict__ fill,
                                              int2* __restrict__ csr) {
    int t = blockIdx.x * blockDim.x + threadIdx.x;
    if (t < NEDGES) {
        int r = ei[t], c = ei[NEDGES + t];
        float nm = dinv[r] * dinv[c];
        int pos = colptr[c] + atomicAdd(&fill[c], 1);
        csr[pos] = make_int2(r, __float_as_int(nm));
    }
}

// h1 = x @ W1 + b1 : wave-per-node, W1^T staged in LDS. HBM-floor: 204.8MB x-read.
__global__ __launch_bounds__(256) void k_gemm1(const float* __restrict__ x, const float* __restrict__ W1,
                                               const float* __restrict__ b1, float* __restrict__ h1) {
    __shared__ float w[HID * FIN]; // w[k*512 + j]
    for (int idx = threadIdx.x; idx < HID * FIN; idx += 256) {
        int j = idx >> 3, k = idx & 7;
        w[k * FIN + j] = W1[idx];
    }
    __syncthreads();
    int lane = threadIdx.x & 63;
    int node = blockIdx.x * 4 + (threadIdx.x >> 6);
    const float* xr = x + (size_t)node * FIN;
    float acc[8] = {0.f,0.f,0.f,0.f,0.f,0.f,0.f,0.f};
#pragma unroll
    for (int tt = 0; tt < 8; tt++) {
        float xv = xr[lane + 64 * tt];   // coalesced 256B/wave
#pragma unroll
        for (int k = 0; k < 8; k++)
            acc[k] += xv * w[k * FIN + lane + 64 * tt];  // 2-way bank alias = free (m136)
    }
    // folded wave reduction: 8x64 partials -> channel (lane>>3)&7 full sum
    {
        bool hi = (lane & 32) != 0;
#pragma unroll
        for (int m = 0; m < 4; m++) {
            float send = hi ? acc[m] : acc[m + 4];
            float recv = __shfl_xor(send, 32, 64);
            acc[m] = (hi ? acc[m + 4] : acc[m]) + recv;
        }
    }
    {
        bool hi = (lane & 16) != 0;
#pragma unroll
        for (int m = 0; m < 2; m++) {
            float send = hi ? acc[m] : acc[m + 2];
            float recv = __shfl_xor(send, 16, 64);
            acc[m] = (hi ? acc[m + 2] : acc[m]) + recv;
        }
    }
    {
        bool hi = (lane & 8) != 0;
        float send = hi ? acc[0] : acc[1];
        float recv = __shfl_xor(send, 8, 64);
        acc[0] = (hi ? acc[1] : acc[0]) + recv;
    }
    acc[0] += __shfl_xor(acc[0], 4, 64);
    acc[0] += __shfl_xor(acc[0], 2, 64);
    acc[0] += __shfl_xor(acc[0], 1, 64);
    if ((lane & 7) == 0) {
        int k = (lane >> 3) & 7;
        h1[(size_t)node * HID + k] = acc[0] + b1[k];
    }
}

// layer-1 aggregation + ELU + GEMM2 (8->64) fused. wave-per-node, lane=(edge-slot, channel).
__global__ __launch_bounds__(256) void k_agg1(const int* __restrict__ colptr, const int2* __restrict__ csr,
                                              const float* __restrict__ h1, const float* __restrict__ A1,
                                              const float* __restrict__ mb1, const float* __restrict__ W2,
                                              const float* __restrict__ b2, float* __restrict__ h2) {
    int lane = threadIdx.x & 63;
    int node = blockIdx.x * 4 + (threadIdx.x >> 6);
    int k = lane & 7, esub = lane >> 3;
    float a1 = A1[k], m1 = mb1[k];
    int s = colptr[node], e = colptr[node + 1];
    float acc = 0.f;
    for (int i = s + esub; i < e; i += 8) {
        int2 ed = csr[i];                       // 8-lane broadcast
        float nm = __int_as_float(ed.y);
        acc += (nm * a1 + m1) * h1[(size_t)ed.x * HID + k];  // 32B contiguous per group
    }
    acc += __shfl_xor(acc, 8, 64);
    acc += __shfl_xor(acc, 16, 64);
    acc += __shfl_xor(acc, 32, 64);
    float hv = acc > 0.f ? acc : expm1f(acc);   // ELU (alpha=1)
    float o = b2[lane];
#pragma unroll
    for (int j = 0; j < 8; j++) {
        float ev = __shfl(hv, j, 64);           // lane j holds channel j
        o += ev * W2[j * NC + lane];
    }
    h2[(size_t)node * NC + lane] = o;           // coalesced 256B
}

// layer-2 aggregation + log_softmax fused. wave-per-node, lane = channel.
__global__ __launch_bounds__(256) void k_agg2(const int* __restrict__ colptr, const int2* __restrict__ csr,
                                              const float* __restrict__ h2, const float* __restrict__ A2,
                                              const float* __restrict__ mb2, float* __restrict__ out) {
    int lane = threadIdx.x & 63;
    int node = blockIdx.x * 4 + (threadIdx.x >> 6);
    float a2 = A2[lane], m2 = mb2[lane];
    int s = colptr[node], e = colptr[node + 1];
    float acc = 0.f;
    int i = s;
    for (; i + 4 <= e; i += 4) {    // 4 independent 256B gathers in flight
        int2 e0 = csr[i], e1 = csr[i + 1], e2 = csr[i + 2], e3 = csr[i + 3];
        float h0 = h2[(size_t)e0.x * NC + lane];
        float h1v = h2[(size_t)e1.x * NC + lane];
        float h2v = h2[(size_t)e2.x * NC + lane];
        float h3 = h2[(size_t)e3.x * NC + lane];
        acc += (__int_as_float(e0.y) * a2 + m2) * h0;
        acc += (__int_as_float(e1.y) * a2 + m2) * h1v;
        acc += (__int_as_float(e2.y) * a2 + m2) * h2v;
        acc += (__int_as_float(e3.y) * a2 + m2) * h3;
    }
    for (; i < e; i++) {
        int2 ed = csr[i];
        acc += (__int_as_float(ed.y) * a2 + m2) * h2[(size_t)ed.x * NC + lane];
    }
    // log_softmax across the 64 lanes
    float m = acc;
#pragma unroll
    for (int o = 32; o >= 1; o >>= 1) m = fmaxf(m, __shfl_xor(m, o, 64));
    float ex = expf(acc - m);
    float ssum = ex;
#pragma unroll
    for (int o = 32; o >= 1; o >>= 1) ssum += __shfl_xor(ssum, o, 64);
    out[(size_t)node * NC + lane] = (acc - m) - logf(ssum);
}

extern "C" void kernel_launch(void* const* d_in, const int* in_sizes, int n_in,
                              void* d_out, int out_size, void* d_ws, size_t ws_size,
                              hipStream_t stream) {
    const float* x    = (const float*)d_in[0];
    const int*   ei   = (const int*)d_in[1];
    const float* W1   = (const float*)d_in[2];
    const float* b1   = (const float*)d_in[3];
    const float* mW1a = (const float*)d_in[4];
    const float* mW1b = (const float*)d_in[5];
    const float* mb1  = (const float*)d_in[6];
    const float* W2   = (const float*)d_in[7];
    const float* b2   = (const float*)d_in[8];
    const float* mW2a = (const float*)d_in[9];
    const float* mW2b = (const float*)d_in[10];
    const float* mb2  = (const float*)d_in[11];

    char* ws = (char*)d_ws;
    int*   deg    = (int*)(ws + OFF_DEG);
    int*   cnt    = (int*)(ws + OFF_CNT);
    int*   fill   = (int*)(ws + OFF_FILL);
    float* dinv   = (float*)(ws + OFF_DINV);
    int*   colptr = (int*)(ws + OFF_COLPTR);
    int*   bsum   = (int*)(ws + OFF_BSUM);
    int*   boff   = (int*)(ws + OFF_BOFF);
    float* A1     = (float*)(ws + OFF_A1);
    float* A2     = (float*)(ws + OFF_A2);
    int2*  csr    = (int2*)(ws + OFF_CSR);
    float* h1     = (float*)(ws + OFF_H1);
    float* h2     = (float*)(ws + OFF_H2);
    float* outp   = (float*)d_out;

    // zero deg/cnt/fill (ws is re-poisoned 0xAA before every timed launch)
    hipMemsetAsync(ws, 0, 1572864, stream);

    const int EB = (NEDGES + 255) / 256;
    const int NB = (NNODES + 255) / 256;
    const int SB = (NNODES + 1023) / 1024; // 98

    k_count  <<<EB, 256, 0, stream>>>(ei, deg, cnt);
    k_dinv   <<<NB, 256, 0, stream>>>(deg, dinv);
    k_scan1  <<<SB, 1024, 0, stream>>>(cnt, colptr, bsum);
    k_scan2  <<<1, 128, 0, stream>>>(bsum, boff, SB);
    k_scan3  <<<SB, 1024, 0, stream>>>(colptr, boff);
    k_precomp<<<1, 64, 0, stream>>>(mW1a, mW1b, mW2a, mW2b, A1, A2);
    k_fill   <<<EB, 256, 0, stream>>>(ei, dinv, colptr, fill, csr);
    k_gemm1  <<<NNODES / 4, 256, 0, stream>>>(x, W1, b1, h1);
    k_agg1   <<<NNODES / 4, 256, 0, stream>>>(colptr, csr, h1, A1, mb1, W2, b2, h2);
    k_agg2   <<<NNODES / 4, 256, 0, stream>>>(colptr, csr, h2, A2, mb2, outp);
}

// Round 4
// 880.055 us; speedup vs baseline: 1.0110x; 1.0110x over previous
//
#include <hip/hip_runtime.h>
#include <hip/hip_bf16.h>
#include <math.h>

#define NNODES 100000
#define NEDGES 3200000
#define FIN 512
#define HID 8
#define NC 64

// ---- workspace layout (bytes). peak ~58.4 MB (proven available: 59.2) ----
// deg/cnt are PADDED x4 (counter i at int-index 4*i, 16B stride) to probe
// L2 line-serialization on atomics. Both dead after scan1 -> h1 overlays them.
#define OFF_DEG      0u          // N ints, stride 4  (1.6 MB)
#define OFF_CNT      1600000u    // N ints, stride 4  (1.6 MB)
#define OFF_DINV     3200000u    // N float (400 KB)
#define OFF_COLPTR   3600000u    // N+1 int (400 KB)
#define OFF_BSUM     4000004u    // <=128 int
#define OFF_BOFF     4000516u    // <=128 int
#define OFF_A1       4001028u    // 8 float
#define OFF_A2       4001060u    // 64 float
#define OFF_AUX      4001316u    // E uint8 ranks (3.2 MB)
#define OFF_CSR      7201320u    // E int2 (25.6 MB), 8B-aligned
#define OFF_H1       0u          // N*8 float (3.2 MB) OVERLAYS deg+cnt (dead)
#define OFF_H2       32801320u   // N*64 float (25.6 MB) -> end 58.4 MB

// count histograms + capture per-edge rank (CSR slot) from the cnt atomic.
__global__ __launch_bounds__(256) void k_count(const int* __restrict__ ei,
                                               int* __restrict__ deg, int* __restrict__ cnt,
                                               unsigned char* __restrict__ aux) {
    int t = blockIdx.x * blockDim.x + threadIdx.x;
    if (t < NEDGES) {
        atomicAdd(&deg[ei[t] << 2], 1);                     // row histogram (padded)
        int rank = atomicAdd(&cnt[ei[NEDGES + t] << 2], 1); // col histogram + rank
        aux[t] = (unsigned char)rank;                       // max in-deg ~70 << 256
    }
}

// block-scan of (padded) cnt -> colptr[i+1]; fused dinv from (padded) deg.
__global__ __launch_bounds__(1024) void k_scan1(const int* __restrict__ cnt,
                                                const int* __restrict__ deg,
                                                float* __restrict__ dinv,
                                                int* __restrict__ colptr, int* __restrict__ bsum) {
    __shared__ int s[1024];
    int t = threadIdx.x, b = blockIdx.x;
    int i = b * 1024 + t;
    int v = (i < NNODES) ? cnt[i << 2] : 0;
    if (i < NNODES) {
        int d = deg[i << 2];
        dinv[i] = (d > 0) ? 1.0f / sqrtf((float)d) : 0.0f;
    }
    s[t] = v; __syncthreads();
    for (int off = 1; off < 1024; off <<= 1) {
        int add = (t >= off) ? s[t - off] : 0;
        __syncthreads();
        s[t] += add;
        __syncthreads();
    }
    if (i < NNODES) colptr[i + 1] = s[t];
    if (t == 1023) bsum[b] = s[1023];
}

__global__ __launch_bounds__(128) void k_scan2(const int* __restrict__ bsum,
                                               int* __restrict__ boff, int nb) {
    __shared__ int s[128];
    int t = threadIdx.x;
    int v = (t < nb) ? bsum[t] : 0;
    s[t] = v; __syncthreads();
    for (int off = 1; off < 128; off <<= 1) {
        int add = (t >= off) ? s[t - off] : 0;
        __syncthreads();
        s[t] += add;
        __syncthreads();
    }
    if (t < nb) boff[t] = s[t] - v; // exclusive
}

__global__ __launch_bounds__(1024) void k_scan3(int* __restrict__ colptr, const int* __restrict__ boff) {
    int i = blockIdx.x * blockDim.x + threadIdx.x;
    if (i < NNODES) colptr[i + 1] += boff[i >> 10];
    if (i == 0) colptr[0] = 0;
}

// Collapse edge-MLP (exact for norm>=0): A_k = sum_j leaky(mWa_j) * mWb[j][k]
__global__ __launch_bounds__(64) void k_precomp(const float* __restrict__ mW1a, const float* __restrict__ mW1b,
                                                const float* __restrict__ mW2a, const float* __restrict__ mW2b,
                                                float* __restrict__ A1, float* __restrict__ A2) {
    int t = threadIdx.x;
    if (t < 8) {
        float s = 0.f;
        for (int j = 0; j < 8; j++) {
            float a = mW1a[j]; a = a > 0.f ? a : 0.2f * a;
            s += a * mW1b[j * 8 + t];
        }
        A1[t] = s;
    }
    if (t < 64) {
        float s = 0.f;
        for (int j = 0; j < 64; j++) {
            float a = mW2a[j]; a = a > 0.f ? a : 0.2f * a;
            s += a * mW2b[j * 64 + t];
        }
        A2[t] = s;
    }
}

// atomic-free CSR fill: slot = colptr[c] + rank (captured in k_count).
__global__ __launch_bounds__(256) void k_fill(const int* __restrict__ ei, const float* __restrict__ dinv,
                                              const int* __restrict__ colptr,
                                              const unsigned char* __restrict__ aux,
                                              int2* __restrict__ csr) {
    int t = blockIdx.x * blockDim.x + threadIdx.x;
    if (t < NEDGES) {
        int r = ei[t], c = ei[NEDGES + t];
        float nm = dinv[r] * dinv[c];
        int pos = colptr[c] + (int)aux[t];
        csr[pos] = make_int2(r, __float_as_int(nm));
    }
}

// h1 = x @ W1 + b1 : wave-per-node, W1^T staged in LDS. HBM-floor: 204.8MB x-read.
__global__ __launch_bounds__(256) void k_gemm1(const float* __restrict__ x, const float* __restrict__ W1,
                                               const float* __restrict__ b1, float* __restrict__ h1) {
    __shared__ float w[HID * FIN]; // w[k*512 + j]
    for (int idx = threadIdx.x; idx < HID * FIN; idx += 256) {
        int j = idx >> 3, k = idx & 7;
        w[k * FIN + j] = W1[idx];
    }
    __syncthreads();
    int lane = threadIdx.x & 63;
    int node = blockIdx.x * 4 + (threadIdx.x >> 6);
    const float* xr = x + (size_t)node * FIN;
    float acc[8] = {0.f,0.f,0.f,0.f,0.f,0.f,0.f,0.f};
#pragma unroll
    for (int tt = 0; tt < 8; tt++) {
        float xv = xr[lane + 64 * tt];   // coalesced 256B/wave
#pragma unroll
        for (int k = 0; k < 8; k++)
            acc[k] += xv * w[k * FIN + lane + 64 * tt];  // 2-way bank alias = free (m136)
    }
    // folded wave reduction: 8x64 partials -> channel (lane>>3)&7 full sum
    {
        bool hi = (lane & 32) != 0;
#pragma unroll
        for (int m = 0; m < 4; m++) {
            float send = hi ? acc[m] : acc[m + 4];
            float recv = __shfl_xor(send, 32, 64);
            acc[m] = (hi ? acc[m + 4] : acc[m]) + recv;
        }
    }
    {
        bool hi = (lane & 16) != 0;
#pragma unroll
        for (int m = 0; m < 2; m++) {
            float send = hi ? acc[m] : acc[m + 2];
            float recv = __shfl_xor(send, 16, 64);
            acc[m] = (hi ? acc[m + 2] : acc[m]) + recv;
        }
    }
    {
        bool hi = (lane & 8) != 0;
        float send = hi ? acc[0] : acc[1];
        float recv = __shfl_xor(send, 8, 64);
        acc[0] = (hi ? acc[1] : acc[0]) + recv;
    }
    acc[0] += __shfl_xor(acc[0], 4, 64);
    acc[0] += __shfl_xor(acc[0], 2, 64);
    acc[0] += __shfl_xor(acc[0], 1, 64);
    if ((lane & 7) == 0) {
        int k = (lane >> 3) & 7;
        h1[(size_t)node * HID + k] = acc[0] + b1[k];
    }
}

// layer-1 aggregation + ELU + GEMM2 (8->64) fused. wave-per-node, lane=(edge-slot, channel).
__global__ __launch_bounds__(256) void k_agg1(const int* __restrict__ colptr, const int2* __restrict__ csr,
                                              const float* __restrict__ h1, const float* __restrict__ A1,
                                              const float* __restrict__ mb1, const float* __restrict__ W2,
                                              const float* __restrict__ b2, float* __restrict__ h2) {
    int lane = threadIdx.x & 63;
    int node = blockIdx.x * 4 + (threadIdx.x >> 6);
    int k = lane & 7, esub = lane >> 3;
    float a1 = A1[k], m1 = mb1[k];
    int s = colptr[node], e = colptr[node + 1];
    float acc = 0.f;
    for (int i = s + esub; i < e; i += 8) {
        int2 ed = csr[i];                       // 8-lane broadcast
        float nm = __int_as_float(ed.y);
        acc += (nm * a1 + m1) * h1[(size_t)ed.x * HID + k];  // 32B contiguous per group
    }
    acc += __shfl_xor(acc, 8, 64);
    acc += __shfl_xor(acc, 16, 64);
    acc += __shfl_xor(acc, 32, 64);
    float hv = acc > 0.f ? acc : expm1f(acc);   // ELU (alpha=1)
    float o = b2[lane];
#pragma unroll
    for (int j = 0; j < 8; j++) {
        float ev = __shfl(hv, j, 64);           // lane j holds channel j
        o += ev * W2[j * NC + lane];
    }
    h2[(size_t)node * NC + lane] = o;           // coalesced 256B
}

// layer-2 aggregation + log_softmax fused. wave-per-node, lane = channel.
__global__ __launch_bounds__(256) void k_agg2(const int* __restrict__ colptr, const int2* __restrict__ csr,
                                              const float* __restrict__ h2, const float* __restrict__ A2,
                                              const float* __restrict__ mb2, float* __restrict__ out) {
    int lane = threadIdx.x & 63;
    int node = blockIdx.x * 4 + (threadIdx.x >> 6);
    float a2 = A2[lane], m2 = mb2[lane];
    int s = colptr[node], e = colptr[node + 1];
    float acc = 0.f;
    int i = s;
    for (; i + 4 <= e; i += 4) {    // 4 independent 256B gathers in flight
        int2 e0 = csr[i], e1 = csr[i + 1], e2 = csr[i + 2], e3 = csr[i + 3];
        float h0 = h2[(size_t)e0.x * NC + lane];
        float h1v = h2[(size_t)e1.x * NC + lane];
        float h2v = h2[(size_t)e2.x * NC + lane];
        float h3 = h2[(size_t)e3.x * NC + lane];
        acc += (__int_as_float(e0.y) * a2 + m2) * h0;
        acc += (__int_as_float(e1.y) * a2 + m2) * h1v;
        acc += (__int_as_float(e2.y) * a2 + m2) * h2v;
        acc += (__int_as_float(e3.y) * a2 + m2) * h3;
    }
    for (; i < e; i++) {
        int2 ed = csr[i];
        acc += (__int_as_float(ed.y) * a2 + m2) * h2[(size_t)ed.x * NC + lane];
    }
    // log_softmax across the 64 lanes
    float m = acc;
#pragma unroll
    for (int o = 32; o >= 1; o >>= 1) m = fmaxf(m, __shfl_xor(m, o, 64));
    float ex = expf(acc - m);
    float ssum = ex;
#pragma unroll
    for (int o = 32; o >= 1; o >>= 1) ssum += __shfl_xor(ssum, o, 64);
    out[(size_t)node * NC + lane] = (acc - m) - logf(ssum);
}

extern "C" void kernel_launch(void* const* d_in, const int* in_sizes, int n_in,
                              void* d_out, int out_size, void* d_ws, size_t ws_size,
                              hipStream_t stream) {
    const float* x    = (const float*)d_in[0];
    const int*   ei   = (const int*)d_in[1];
    const float* W1   = (const float*)d_in[2];
    const float* b1   = (const float*)d_in[3];
    const float* mW1a = (const float*)d_in[4];
    const float* mW1b = (const float*)d_in[5];
    const float* mb1  = (const float*)d_in[6];
    const float* W2   = (const float*)d_in[7];
    const float* b2   = (const float*)d_in[8];
    const float* mW2a = (const float*)d_in[9];
    const float* mW2b = (const float*)d_in[10];
    const float* mb2  = (const float*)d_in[11];

    char* ws = (char*)d_ws;
    int*   deg    = (int*)(ws + OFF_DEG);
    int*   cnt    = (int*)(ws + OFF_CNT);
    float* dinv   = (float*)(ws + OFF_DINV);
    int*   colptr = (int*)(ws + OFF_COLPTR);
    int*   bsum   = (int*)(ws + OFF_BSUM);
    int*   boff   = (int*)(ws + OFF_BOFF);
    float* A1     = (float*)(ws + OFF_A1);
    float* A2     = (float*)(ws + OFF_A2);
    unsigned char* aux = (unsigned char*)(ws + OFF_AUX);
    int2*  csr    = (int2*)(ws + OFF_CSR);
    float* h1     = (float*)(ws + OFF_H1);   // overlays deg+cnt (dead after scan1)
    float* h2     = (float*)(ws + OFF_H2);
    float* outp   = (float*)d_out;

    // zero padded deg+cnt (3.2 MB); ws is re-poisoned 0xAA before every timed launch
    hipMemsetAsync(ws, 0, 3200000, stream);

    const int EB = (NEDGES + 255) / 256;
    const int SB = (NNODES + 1023) / 1024; // 98

    k_count  <<<EB, 256, 0, stream>>>(ei, deg, cnt, aux);
    k_scan1  <<<SB, 1024, 0, stream>>>(cnt, deg, dinv, colptr, bsum);
    k_scan2  <<<1, 128, 0, stream>>>(bsum, boff, SB);
    k_scan3  <<<SB, 1024, 0, stream>>>(colptr, boff);
    k_precomp<<<1, 64, 0, stream>>>(mW1a, mW1b, mW2a, mW2b, A1, A2);
    k_fill   <<<EB, 256, 0, stream>>>(ei, dinv, colptr, aux, csr);
    k_gemm1  <<<NNODES / 4, 256, 0, stream>>>(x, W1, b1, h1);   // after fill: h1 overlays deg/cnt
    k_agg1   <<<NNODES / 4, 256, 0, stream>>>(colptr, csr, h1, A1, mb1, W2, b2, h2);
    k_agg2   <<<NNODES / 4, 256, 0, stream>>>(colptr, csr, h2, A2, mb2, outp);
}

// Round 11
// 865.543 us; speedup vs baseline: 1.0280x; 1.0168x over previous
//
#include <hip/hip_runtime.h>
#include <hip/hip_bf16.h>
#include <math.h>

#define NNODES 100000
#define NEDGES 3200000
#define FIN 512
#define HID 8
#define NC 64

// deg histogram: LDS-privatized range x chunk (atomic-free)
#define NRANGE 8
#define NCHUNK 32
#define ECHUNK (NEDGES / NCHUNK)   // 100000 exact
#define RBINS  12500               // NNODES / NRANGE exact
#define RPAD   12512               // slab row pad

// ---- workspace layout (bytes). peak ~55.6 MB ----
// slab (12.8 MB) overlays CSR region (csr written later, in k_fill).
// aux (edge ranks) dead after k_fill -> h1 overlays it.
#define OFF_CNT      0u          // N int (400 KB)
#define OFF_DINV     400000u     // N float (400 KB)
#define OFF_COLPTR   800000u     // N+1 int
#define OFF_BSUM     1200004u    // <=128 int
#define OFF_BOFF     1200516u    // <=128 int
#define OFF_A1       1201028u    // 8 float
#define OFF_A2       1201060u    // 64 float
#define OFF_AUX      1201316u    // E uint8 ranks (3.2 MB)
#define OFF_H1       1201316u    // N*8 float OVERLAYS aux (dead after k_fill)
#define OFF_CSR      4401320u    // E int2 (25.6 MB), 8B-aligned; slab overlays (12.8 MB)
#define OFF_H2       30001320u   // N*64 float (25.6 MB) -> end 55.6 MB

// deg histogram, atomic-free: block (ri,ci) = (blockIdx&7, blockIdx>>3)
// LDS-histograms rows of chunk ci falling in range ri; writes private slab.
__global__ __launch_bounds__(1024) void k_hist(const int* __restrict__ ei, int* __restrict__ slab) {
    __shared__ int lh[RBINS];
    int ri = blockIdx.x & 7, ci = blockIdx.x >> 3;
    for (int b = threadIdx.x; b < RBINS; b += 1024) lh[b] = 0;
    __syncthreads();
    int base = ri * RBINS;
    const int* rows = ei + (size_t)ci * ECHUNK;
    for (int t = threadIdx.x; t < ECHUNK; t += 1024) {
        int r = rows[t] - base;
        if ((unsigned)r < RBINS) atomicAdd(&lh[r], 1);   // LDS atomic: cheap
    }
    __syncthreads();
    int* out = slab + (size_t)blockIdx.x * RPAD;
    for (int b = threadIdx.x; b < RBINS; b += 1024) out[b] = lh[b];
}

// deg[i] = sum over chunks of slab; dinv = deg^-0.5 (exact int sum, same math).
__global__ __launch_bounds__(256) void k_reduce(const int* __restrict__ slab, float* __restrict__ dinv) {
    int i = blockIdx.x * 256 + threadIdx.x;
    if (i >= NNODES) return;
    int ri = i / RBINS, b = i - ri * RBINS;
    int s = 0;
#pragma unroll 4
    for (int ci = 0; ci < NCHUNK; ci++)
        s += slab[(size_t)(ci * NRANGE + ri) * RPAD + b];   // coalesced per ci
    dinv[i] = (s > 0) ? 1.0f / sqrtf((float)s) : 0.0f;
}

// cnt histogram + per-edge rank (CSR slot) from the atomic return. (3.2M atomics)
__global__ __launch_bounds__(256) void k_count(const int* __restrict__ ei,
                                               int* __restrict__ cnt,
                                               unsigned char* __restrict__ aux) {
    int t = blockIdx.x * blockDim.x + threadIdx.x;
    if (t < NEDGES) {
        int rank = atomicAdd(&cnt[ei[NEDGES + t]], 1);
        aux[t] = (unsigned char)rank;   // max in-deg ~70 << 256
    }
}

// block-scan of cnt -> colptr[i+1].
__global__ __launch_bounds__(1024) void k_scan1(const int* __restrict__ cnt,
                                                int* __restrict__ colptr, int* __restrict__ bsum) {
    __shared__ int s[1024];
    int t = threadIdx.x, b = blockIdx.x;
    int i = b * 1024 + t;
    int v = (i < NNODES) ? cnt[i] : 0;
    s[t] = v; __syncthreads();
    for (int off = 1; off < 1024; off <<= 1) {
        int add = (t >= off) ? s[t - off] : 0;
        __syncthreads();
        s[t] += add;
        __syncthreads();
    }
    if (i < NNODES) colptr[i + 1] = s[t];
    if (t == 1023) bsum[b] = s[1023];
}

__global__ __launch_bounds__(128) void k_scan2(const int* __restrict__ bsum,
                                               int* __restrict__ boff, int nb) {
    __shared__ int s[128];
    int t = threadIdx.x;
    int v = (t < nb) ? bsum[t] : 0;
    s[t] = v; __syncthreads();
    for (int off = 1; off < 128; off <<= 1) {
        int add = (t >= off) ? s[t - off] : 0;
        __syncthreads();
        s[t] += add;
        __syncthreads();
    }
    if (t < nb) boff[t] = s[t] - v; // exclusive
}

__global__ __launch_bounds__(1024) void k_scan3(int* __restrict__ colptr, const int* __restrict__ boff) {
    int i = blockIdx.x * blockDim.x + threadIdx.x;
    if (i < NNODES) colptr[i + 1] += boff[i >> 10];
    if (i == 0) colptr[0] = 0;
}

// Collapse edge-MLP (exact for norm>=0): A_k = sum_j leaky(mWa_j) * mWb[j][k]
__global__ __launch_bounds__(64) void k_precomp(const float* __restrict__ mW1a, const float* __restrict__ mW1b,
                                                const float* __restrict__ mW2a, const float* __restrict__ mW2b,
                                                float* __restrict__ A1, float* __restrict__ A2) {
    int t = threadIdx.x;
    if (t < 8) {
        float s = 0.f;
        for (int j = 0; j < 8; j++) {
            float a = mW1a[j]; a = a > 0.f ? a : 0.2f * a;
            s += a * mW1b[j * 8 + t];
        }
        A1[t] = s;
    }
    if (t < 64) {
        float s = 0.f;
        for (int j = 0; j < 64; j++) {
            float a = mW2a[j]; a = a > 0.f ? a : 0.2f * a;
            s += a * mW2b[j * 64 + t];
        }
        A2[t] = s;
    }
}

// atomic-free CSR fill: slot = colptr[c] + rank (captured in k_count).
__global__ __launch_bounds__(256) void k_fill(const int* __restrict__ ei, const float* __restrict__ dinv,
                                              const int* __restrict__ colptr,
                                              const unsigned char* __restrict__ aux,
                                              int2* __restrict__ csr) {
    int t = blockIdx.x * blockDim.x + threadIdx.x;
    if (t < NEDGES) {
        int r = ei[t], c = ei[NEDGES + t];
        float nm = dinv[r] * dinv[c];
        int pos = colptr[c] + (int)aux[t];
        csr[pos] = make_int2(r, __float_as_int(nm));
    }
}

// h1 = x @ W1 + b1 : wave-per-node, W1 register-resident (no LDS).
__global__ __launch_bounds__(256) void k_gemm1(const float* __restrict__ x, const float* __restrict__ W1,
                                               const float* __restrict__ b1, float* __restrict__ h1) {
    int lane = threadIdx.x & 63;
    int node = blockIdx.x * 4 + (threadIdx.x >> 6);
    float w[8][8]; // w[4*tf+m][k] = W1[(4*(lane+64*tf)+m)*8 + k]
#pragma unroll
    for (int tf = 0; tf < 2; tf++) {
        int jf = lane + 64 * tf;
#pragma unroll
        for (int m = 0; m < 4; m++) {
            const float4* Wr = (const float4*)(W1 + (size_t)(4 * jf + m) * 8);
            float4 lo = Wr[0], hi = Wr[1];
            int r = 4 * tf + m;
            w[r][0] = lo.x; w[r][1] = lo.y; w[r][2] = lo.z; w[r][3] = lo.w;
            w[r][4] = hi.x; w[r][5] = hi.y; w[r][6] = hi.z; w[r][7] = hi.w;
        }
    }
    const float4* xr = (const float4*)(x + (size_t)node * FIN);
    float acc[8] = {0.f,0.f,0.f,0.f,0.f,0.f,0.f,0.f};
#pragma unroll
    for (int tf = 0; tf < 2; tf++) {
        float4 xv = xr[lane + 64 * tf];   // coalesced 1KB/wave-inst
        float xs[4] = {xv.x, xv.y, xv.z, xv.w};
#pragma unroll
        for (int m = 0; m < 4; m++)
#pragma unroll
            for (int k = 0; k < 8; k++)
                acc[k] += xs[m] * w[4 * tf + m][k];
    }
    // folded wave reduction: 8x64 partials -> channel (lane>>3)&7 full sum
    {
        bool hi = (lane & 32) != 0;
#pragma unroll
        for (int m = 0; m < 4; m++) {
            float send = hi ? acc[m] : acc[m + 4];
            float recv = __shfl_xor(send, 32, 64);
            acc[m] = (hi ? acc[m + 4] : acc[m]) + recv;
        }
    }
    {
        bool hi = (lane & 16) != 0;
#pragma unroll
        for (int m = 0; m < 2; m++) {
            float send = hi ? acc[m] : acc[m + 2];
            float recv = __shfl_xor(send, 16, 64);
            acc[m] = (hi ? acc[m + 2] : acc[m]) + recv;
        }
    }
    {
        bool hi = (lane & 8) != 0;
        float send = hi ? acc[0] : acc[1];
        float recv = __shfl_xor(send, 8, 64);
        acc[0] = (hi ? acc[1] : acc[0]) + recv;
    }
    acc[0] += __shfl_xor(acc[0], 4, 64);
    acc[0] += __shfl_xor(acc[0], 2, 64);
    acc[0] += __shfl_xor(acc[0], 1, 64);
    if ((lane & 7) == 0) {
        int k = (lane >> 3) & 7;
        h1[(size_t)node * HID + k] = acc[0] + b1[k];
    }
}

// layer-1 aggregation + ELU + GEMM2 (8->64) fused. wave-per-node, lane=(edge-slot, channel).
__global__ __launch_bounds__(256) void k_agg1(const int* __restrict__ colptr, const int2* __restrict__ csr,
                                              const float* __restrict__ h1, const float* __restrict__ A1,
                                              const float* __restrict__ mb1, const float* __restrict__ W2,
                                              const float* __restrict__ b2, float* __restrict__ h2) {
    int lane = threadIdx.x & 63;
    int node = blockIdx.x * 4 + (threadIdx.x >> 6);
    int k = lane & 7, esub = lane >> 3;
    float a1 = A1[k], m1 = mb1[k];
    int s = colptr[node], e = colptr[node + 1];
    float acc = 0.f;
    for (int i = s + esub; i < e; i += 8) {
        int2 ed = csr[i];                       // 8-lane broadcast
        float nm = __int_as_float(ed.y);
        acc += (nm * a1 + m1) * h1[(size_t)ed.x * HID + k];  // 32B contiguous per group
    }
    acc += __shfl_xor(acc, 8, 64);
    acc += __shfl_xor(acc, 16, 64);
    acc += __shfl_xor(acc, 32, 64);
    float hv = acc > 0.f ? acc : expm1f(acc);   // ELU (alpha=1)
    float o = b2[lane];
#pragma unroll
    for (int j = 0; j < 8; j++) {
        float ev = __shfl(hv, j, 64);           // lane j holds channel j
        o += ev * W2[j * NC + lane];
    }
    h2[(size_t)node * NC + lane] = o;           // coalesced 256B
}

// layer-2 aggregation + log_softmax fused. wave-per-node, lane = channel.
__global__ __launch_bounds__(256) void k_agg2(const int* __restrict__ colptr, const int2* __restrict__ csr,
                                              const float* __restrict__ h2, const float* __restrict__ A2,
                                              const float* __restrict__ mb2, float* __restrict__ out) {
    int lane = threadIdx.x & 63;
    int node = blockIdx.x * 4 + (threadIdx.x >> 6);
    float a2 = A2[lane], m2 = mb2[lane];
    int s = colptr[node], e = colptr[node + 1];
    float acc = 0.f;
    int i = s;
    for (; i + 4 <= e; i += 4) {    // 4 independent 256B gathers in flight
        int2 e0 = csr[i], e1 = csr[i + 1], e2 = csr[i + 2], e3 = csr[i + 3];
        float h0 = h2[(size_t)e0.x * NC + lane];
        float h1v = h2[(size_t)e1.x * NC + lane];
        float h2v = h2[(size_t)e2.x * NC + lane];
        float h3 = h2[(size_t)e3.x * NC + lane];
        acc += (__int_as_float(e0.y) * a2 + m2) * h0;
        acc += (__int_as_float(e1.y) * a2 + m2) * h1v;
        acc += (__int_as_float(e2.y) * a2 + m2) * h2v;
        acc += (__int_as_float(e3.y) * a2 + m2) * h3;
    }
    for (; i < e; i++) {
        int2 ed = csr[i];
        acc += (__int_as_float(ed.y) * a2 + m2) * h2[(size_t)ed.x * NC + lane];
    }
    // log_softmax across the 64 lanes
    float m = acc;
#pragma unroll
    for (int o = 32; o >= 1; o >>= 1) m = fmaxf(m, __shfl_xor(m, o, 64));
    float ex = expf(acc - m);
    float ssum = ex;
#pragma unroll
    for (int o = 32; o >= 1; o >>= 1) ssum += __shfl_xor(ssum, o, 64);
    out[(size_t)node * NC + lane] = (acc - m) - logf(ssum);
}

extern "C" void kernel_launch(void* const* d_in, const int* in_sizes, int n_in,
                              void* d_out, int out_size, void* d_ws, size_t ws_size,
                              hipStream_t stream) {
    const float* x    = (const float*)d_in[0];
    const int*   ei   = (const int*)d_in[1];
    const float* W1   = (const float*)d_in[2];
    const float* b1   = (const float*)d_in[3];
    const float* mW1a = (const float*)d_in[4];
    const float* mW1b = (const float*)d_in[5];
    const float* mb1  = (const float*)d_in[6];
    const float* W2   = (const float*)d_in[7];
    const float* b2   = (const float*)d_in[8];
    const float* mW2a = (const float*)d_in[9];
    const float* mW2b = (const float*)d_in[10];
    const float* mb2  = (const float*)d_in[11];

    char* ws = (char*)d_ws;
    int*   cnt    = (int*)(ws + OFF_CNT);
    float* dinv   = (float*)(ws + OFF_DINV);
    int*   colptr = (int*)(ws + OFF_COLPTR);
    int*   bsum   = (int*)(ws + OFF_BSUM);
    int*   boff   = (int*)(ws + OFF_BOFF);
    float* A1     = (float*)(ws + OFF_A1);
    float* A2     = (float*)(ws + OFF_A2);
    unsigned char* aux = (unsigned char*)(ws + OFF_AUX);
    int*   slab   = (int*)(ws + OFF_CSR);    // overlays csr (dead until k_fill)
    int2*  csr    = (int2*)(ws + OFF_CSR);
    float* h1     = (float*)(ws + OFF_H1);   // overlays aux (dead after k_fill)
    float* h2     = (float*)(ws + OFF_H2);
    float* outp   = (float*)d_out;

    // zero cnt only (400 KB); ws is re-poisoned 0xAA before every timed launch
    hipMemsetAsync(ws, 0, 400000, stream);

    const int EB = (NEDGES + 255) / 256;
    const int SB = (NNODES + 1023) / 1024; // 98

    k_hist   <<<NRANGE * NCHUNK, 1024, 0, stream>>>(ei, slab);       // deg, atomic-free
    k_reduce <<<(NNODES + 255) / 256, 256, 0, stream>>>(slab, dinv);
    k_count  <<<EB, 256, 0, stream>>>(ei, cnt, aux);                 // cnt + ranks
    k_scan1  <<<SB, 1024, 0, stream>>>(cnt, colptr, bsum);
    k_scan2  <<<1, 128, 0, stream>>>(bsum, boff, SB);
    k_scan3  <<<SB, 1024, 0, stream>>>(colptr, boff);
    k_precomp<<<1, 64, 0, stream>>>(mW1a, mW1b, mW2a, mW2b, A1, A2);
    k_fill   <<<EB, 256, 0, stream>>>(ei, dinv, colptr, aux, csr);   // csr overwrites slab
    k_gemm1  <<<NNODES / 4, 256, 0, stream>>>(x, W1, b1, h1);        // h1 overlays aux
    k_agg1   <<<NNODES / 4, 256, 0, stream>>>(colptr, csr, h1, A1, mb1, W2, b2, h2);
    k_agg2   <<<NNODES / 4, 256, 0, stream>>>(colptr, csr, h2, A2, mb2, outp);
}

// Round 14
// 768.866 us; speedup vs baseline: 1.1572x; 1.1257x over previous
//
#include <hip/hip_runtime.h>
#include <hip/hip_bf16.h>
#include <math.h>

#define NNODES 100000
#define NEDGES 3200000
#define FIN 512
#define HID 8
#define NC 64

// deg histogram: LDS-privatized range x chunk (atomic-free)
#define NRANGE 8
#define NCHUNK 32
#define ECHUNK (NEDGES / NCHUNK)   // 100000 exact
#define RBINS  12500               // NNODES / NRANGE exact
#define RPAD   12512               // slab row pad

// ---- workspace layout (bytes). peak ~55.6 MB ----
#define OFF_CNT      0u          // N int (400 KB)
#define OFF_DINV     400000u     // N float (400 KB)
#define OFF_COLPTR   800000u     // N+1 int
#define OFF_BSUM     1200004u    // <=128 int
#define OFF_BOFF     1200516u    // <=128 int
#define OFF_A1       1201028u    // 8 float
#define OFF_A2       1201060u    // 64 float
#define OFF_AUX      1201316u    // E uint8 ranks (3.2 MB)
#define OFF_H1       1201316u    // N*8 float OVERLAYS aux (dead after k_fill)
#define OFF_CSR      4401320u    // E int2 (25.6 MB); slab overlays (12.8 MB)
#define OFF_H2       30001320u   // N*64 float (25.6 MB) -> end 55.6 MB

__global__ __launch_bounds__(1024) void k_hist(const int* __restrict__ ei, int* __restrict__ slab) {
    __shared__ int lh[RBINS];
    int ri = blockIdx.x & 7, ci = blockIdx.x >> 3;
    for (int b = threadIdx.x; b < RBINS; b += 1024) lh[b] = 0;
    __syncthreads();
    int base = ri * RBINS;
    const int* rows = ei + (size_t)ci * ECHUNK;
    for (int t = threadIdx.x; t < ECHUNK; t += 1024) {
        int r = rows[t] - base;
        if ((unsigned)r < RBINS) atomicAdd(&lh[r], 1);
    }
    __syncthreads();
    int* out = slab + (size_t)blockIdx.x * RPAD;
    for (int b = threadIdx.x; b < RBINS; b += 1024) out[b] = lh[b];
}

__global__ __launch_bounds__(256) void k_reduce(const int* __restrict__ slab, float* __restrict__ dinv) {
    int i = blockIdx.x * 256 + threadIdx.x;
    if (i >= NNODES) return;
    int ri = i / RBINS, b = i - ri * RBINS;
    int s = 0;
#pragma unroll 4
    for (int ci = 0; ci < NCHUNK; ci++)
        s += slab[(size_t)(ci * NRANGE + ri) * RPAD + b];
    dinv[i] = (s > 0) ? 1.0f / sqrtf((float)s) : 0.0f;
}

__global__ __launch_bounds__(256) void k_count(const int* __restrict__ ei,
                                               int* __restrict__ cnt,
                                               unsigned char* __restrict__ aux) {
    int t = blockIdx.x * blockDim.x + threadIdx.x;
    if (t < NEDGES) {
        int rank = atomicAdd(&cnt[ei[NEDGES + t]], 1);
        aux[t] = (unsigned char)rank;
    }
}

__global__ __launch_bounds__(1024) void k_scan1(const int* __restrict__ cnt,
                                                int* __restrict__ colptr, int* __restrict__ bsum) {
    __shared__ int s[1024];
    int t = threadIdx.x, b = blockIdx.x;
    int i = b * 1024 + t;
    int v = (i < NNODES) ? cnt[i] : 0;
    s[t] = v; __syncthreads();
    for (int off = 1; off < 1024; off <<= 1) {
        int add = (t >= off) ? s[t - off] : 0;
        __syncthreads();
        s[t] += add;
        __syncthreads();
    }
    if (i < NNODES) colptr[i + 1] = s[t];
    if (t == 1023) bsum[b] = s[1023];
}

__global__ __launch_bounds__(128) void k_scan2(const int* __restrict__ bsum,
                                               int* __restrict__ boff, int nb) {
    __shared__ int s[128];
    int t = threadIdx.x;
    int v = (t < nb) ? bsum[t] : 0;
    s[t] = v; __syncthreads();
    for (int off = 1; off < 128; off <<= 1) {
        int add = (t >= off) ? s[t - off] : 0;
        __syncthreads();
        s[t] += add;
        __syncthreads();
    }
    if (t < nb) boff[t] = s[t] - v;
}

__global__ __launch_bounds__(1024) void k_scan3(int* __restrict__ colptr, const int* __restrict__ boff) {
    int i = blockIdx.x * blockDim.x + threadIdx.x;
    if (i < NNODES) colptr[i + 1] += boff[i >> 10];
    if (i == 0) colptr[0] = 0;
}

__global__ __launch_bounds__(64) void k_precomp(const float* __restrict__ mW1a, const float* __restrict__ mW1b,
                                                const float* __restrict__ mW2a, const float* __restrict__ mW2b,
                                                float* __restrict__ A1, float* __restrict__ A2) {
    int t = threadIdx.x;
    if (t < 8) {
        float s = 0.f;
        for (int j = 0; j < 8; j++) {
            float a = mW1a[j]; a = a > 0.f ? a : 0.2f * a;
            s += a * mW1b[j * 8 + t];
        }
        A1[t] = s;
    }
    if (t < 64) {
        float s = 0.f;
        for (int j = 0; j < 64; j++) {
            float a = mW2a[j]; a = a > 0.f ? a : 0.2f * a;
            s += a * mW2b[j * 64 + t];
        }
        A2[t] = s;
    }
}

__global__ __launch_bounds__(256) void k_fill(const int* __restrict__ ei, const float* __restrict__ dinv,
                                              const int* __restrict__ colptr,
                                              const unsigned char* __restrict__ aux,
                                              int2* __restrict__ csr) {
    int t = blockIdx.x * blockDim.x + threadIdx.x;
    if (t < NEDGES) {
        int r = ei[t], c = ei[NEDGES + t];
        float nm = dinv[r] * dinv[c];
        int pos = colptr[c] + (int)aux[t];
        csr[pos] = make_int2(r, __float_as_int(nm));
    }
}

// h1 = x @ W1 + b1 : wave-per-node, W1^T staged in LDS (R3-proven design).
// R11 post-mortem: register-resident W spilled (VGPR=32!) -> 186us latency-bound.
// LDS path: 8 ds_read_b32 per x-scalar, 2-way bank alias (free, m136); HBM floor ~33us.
__global__ __launch_bounds__(256) void k_gemm1(const float* __restrict__ x, const float* __restrict__ W1,
                                               const float* __restrict__ b1, float* __restrict__ h1) {
    __shared__ float w[HID * FIN]; // w[k*512 + j]
    for (int idx = threadIdx.x; idx < HID * FIN; idx += 256) {
        int j = idx >> 3, k = idx & 7;
        w[k * FIN + j] = W1[idx];
    }
    __syncthreads();
    int lane = threadIdx.x & 63;
    int node = blockIdx.x * 4 + (threadIdx.x >> 6);
    const float* xr = x + (size_t)node * FIN;
    float acc[8] = {0.f,0.f,0.f,0.f,0.f,0.f,0.f,0.f};
#pragma unroll
    for (int tt = 0; tt < 8; tt++) {
        float xv = xr[lane + 64 * tt];   // coalesced 256B/wave
#pragma unroll
        for (int k = 0; k < 8; k++)
            acc[k] += xv * w[k * FIN + lane + 64 * tt];  // 2-way bank alias = free
    }
    // folded wave reduction: 8x64 partials -> channel (lane>>3)&7 full sum
    {
        bool hi = (lane & 32) != 0;
#pragma unroll
        for (int m = 0; m < 4; m++) {
            float send = hi ? acc[m] : acc[m + 4];
            float recv = __shfl_xor(send, 32, 64);
            acc[m] = (hi ? acc[m + 4] : acc[m]) + recv;
        }
    }
    {
        bool hi = (lane & 16) != 0;
#pragma unroll
        for (int m = 0; m < 2; m++) {
            float send = hi ? acc[m] : acc[m + 2];
            float recv = __shfl_xor(send, 16, 64);
            acc[m] = (hi ? acc[m + 2] : acc[m]) + recv;
        }
    }
    {
        bool hi = (lane & 8) != 0;
        float send = hi ? acc[0] : acc[1];
        float recv = __shfl_xor(send, 8, 64);
        acc[0] = (hi ? acc[1] : acc[0]) + recv;
    }
    acc[0] += __shfl_xor(acc[0], 4, 64);
    acc[0] += __shfl_xor(acc[0], 2, 64);
    acc[0] += __shfl_xor(acc[0], 1, 64);
    if ((lane & 7) == 0) {
        int k = (lane >> 3) & 7;
        h1[(size_t)node * HID + k] = acc[0] + b1[k];
    }
}

// layer-1 aggregation + ELU + GEMM2 (8->64) fused. wave-per-node, lane=(edge-slot, channel).
__global__ __launch_bounds__(256) void k_agg1(const int* __restrict__ colptr, const int2* __restrict__ csr,
                                              const float* __restrict__ h1, const float* __restrict__ A1,
                                              const float* __restrict__ mb1, const float* __restrict__ W2,
                                              const float* __restrict__ b2, float* __restrict__ h2) {
    int lane = threadIdx.x & 63;
    int node = blockIdx.x * 4 + (threadIdx.x >> 6);
    int k = lane & 7, esub = lane >> 3;
    float a1 = A1[k], m1 = mb1[k];
    int s = colptr[node], e = colptr[node + 1];
    float acc = 0.f;
    for (int i = s + esub; i < e; i += 8) {
        int2 ed = csr[i];
        float nm = __int_as_float(ed.y);
        acc += (nm * a1 + m1) * h1[(size_t)ed.x * HID + k];
    }
    acc += __shfl_xor(acc, 8, 64);
    acc += __shfl_xor(acc, 16, 64);
    acc += __shfl_xor(acc, 32, 64);
    float hv = acc > 0.f ? acc : expm1f(acc);   // ELU (alpha=1)
    float o = b2[lane];
#pragma unroll
    for (int j = 0; j < 8; j++) {
        float ev = __shfl(hv, j, 64);
        o += ev * W2[j * NC + lane];
    }
    h2[(size_t)node * NC + lane] = o;
}

// layer-2 aggregation + log_softmax fused. wave-per-node, lane = channel.
__global__ __launch_bounds__(256) void k_agg2(const int* __restrict__ colptr, const int2* __restrict__ csr,
                                              const float* __restrict__ h2, const float* __restrict__ A2,
                                              const float* __restrict__ mb2, float* __restrict__ out) {
    int lane = threadIdx.x & 63;
    int node = blockIdx.x * 4 + (threadIdx.x >> 6);
    float a2 = A2[lane], m2 = mb2[lane];
    int s = colptr[node], e = colptr[node + 1];
    float acc = 0.f;
    int i = s;
    for (; i + 4 <= e; i += 4) {
        int2 e0 = csr[i], e1 = csr[i + 1], e2 = csr[i + 2], e3 = csr[i + 3];
        float h0 = h2[(size_t)e0.x * NC + lane];
        float h1v = h2[(size_t)e1.x * NC + lane];
        float h2v = h2[(size_t)e2.x * NC + lane];
        float h3 = h2[(size_t)e3.x * NC + lane];
        acc += (__int_as_float(e0.y) * a2 + m2) * h0;
        acc += (__int_as_float(e1.y) * a2 + m2) * h1v;
        acc += (__int_as_float(e2.y) * a2 + m2) * h2v;
        acc += (__int_as_float(e3.y) * a2 + m2) * h3;
    }
    for (; i < e; i++) {
        int2 ed = csr[i];
        acc += (__int_as_float(ed.y) * a2 + m2) * h2[(size_t)ed.x * NC + lane];
    }
    float m = acc;
#pragma unroll
    for (int o = 32; o >= 1; o >>= 1) m = fmaxf(m, __shfl_xor(m, o, 64));
    float ex = expf(acc - m);
    float ssum = ex;
#pragma unroll
    for (int o = 32; o >= 1; o >>= 1) ssum += __shfl_xor(ssum, o, 64);
    out[(size_t)node * NC + lane] = (acc - m) - logf(ssum);
}

extern "C" void kernel_launch(void* const* d_in, const int* in_sizes, int n_in,
                              void* d_out, int out_size, void* d_ws, size_t ws_size,
                              hipStream_t stream) {
    const float* x    = (const float*)d_in[0];
    const int*   ei   = (const int*)d_in[1];
    const float* W1   = (const float*)d_in[2];
    const float* b1   = (const float*)d_in[3];
    const float* mW1a = (const float*)d_in[4];
    const float* mW1b = (const float*)d_in[5];
    const float* mb1  = (const float*)d_in[6];
    const float* W2   = (const float*)d_in[7];
    const float* b2   = (const float*)d_in[8];
    const float* mW2a = (const float*)d_in[9];
    const float* mW2b = (const float*)d_in[10];
    const float* mb2  = (const float*)d_in[11];

    char* ws = (char*)d_ws;
    int*   cnt    = (int*)(ws + OFF_CNT);
    float* dinv   = (float*)(ws + OFF_DINV);
    int*   colptr = (int*)(ws + OFF_COLPTR);
    int*   bsum   = (int*)(ws + OFF_BSUM);
    int*   boff   = (int*)(ws + OFF_BOFF);
    float* A1     = (float*)(ws + OFF_A1);
    float* A2     = (float*)(ws + OFF_A2);
    unsigned char* aux = (unsigned char*)(ws + OFF_AUX);
    int*   slab   = (int*)(ws + OFF_CSR);    // overlays csr (dead until k_fill)
    int2*  csr    = (int2*)(ws + OFF_CSR);
    float* h1     = (float*)(ws + OFF_H1);   // overlays aux (dead after k_fill)
    float* h2     = (float*)(ws + OFF_H2);
    float* outp   = (float*)d_out;

    hipMemsetAsync(ws, 0, 400000, stream);

    const int EB = (NEDGES + 255) / 256;
    const int SB = (NNODES + 1023) / 1024; // 98

    k_hist   <<<NRANGE * NCHUNK, 1024, 0, stream>>>(ei, slab);
    k_reduce <<<(NNODES + 255) / 256, 256, 0, stream>>>(slab, dinv);
    k_count  <<<EB, 256, 0, stream>>>(ei, cnt, aux);
    k_scan1  <<<SB, 1024, 0, stream>>>(cnt, colptr, bsum);
    k_scan2  <<<1, 128, 0, stream>>>(bsum, boff, SB);
    k_scan3  <<<SB, 1024, 0, stream>>>(colptr, boff);
    k_precomp<<<1, 64, 0, stream>>>(mW1a, mW1b, mW2a, mW2b, A1, A2);
    k_fill   <<<EB, 256, 0, stream>>>(ei, dinv, colptr, aux, csr);
    k_gemm1  <<<NNODES / 4, 256, 0, stream>>>(x, W1, b1, h1);
    k_agg1   <<<NNODES / 4, 256, 0, stream>>>(colptr, csr, h1, A1, mb1, W2, b2, h2);
    k_agg2   <<<NNODES / 4, 256, 0, stream>>>(colptr, csr, h2, A2, mb2, outp);
}